// Round 1
// baseline (295.993 us; speedup 1.0000x reference)
//
#include <hip/hip_runtime.h>
#include <hip/hip_bf16.h>

#define N_HEAD 8
#define D_MODEL 512
#define D_HEAD 64
#define D_HIDDEN 2048
#define NTOK 64
#define BATCH 4096

typedef __attribute__((ext_vector_type(4))) float f32x4;
typedef __attribute__((ext_vector_type(8))) short short8;
typedef __attribute__((ext_vector_type(8))) unsigned short u16x8;

__device__ __forceinline__ float bf2f(unsigned short u) {
    return __uint_as_float(((unsigned int)u) << 16);
}
__device__ __forceinline__ unsigned short f2bf(float f) {
    unsigned int b = __float_as_uint(f);
    b += 0x7fffu + ((b >> 16) & 1u);
    return (unsigned short)(b >> 16);
}
__device__ __forceinline__ float wave_sum(float v) {
    v += __shfl_xor(v, 32); v += __shfl_xor(v, 16); v += __shfl_xor(v, 8);
    v += __shfl_xor(v, 4);  v += __shfl_xor(v, 2);  v += __shfl_xor(v, 1);
    return v;
}
__device__ __forceinline__ float wave_max(float v) {
    v = fmaxf(v, __shfl_xor(v, 32)); v = fmaxf(v, __shfl_xor(v, 16));
    v = fmaxf(v, __shfl_xor(v, 8));  v = fmaxf(v, __shfl_xor(v, 4));
    v = fmaxf(v, __shfl_xor(v, 2));  v = fmaxf(v, __shfl_xor(v, 1));
    return v;
}

// K0: u[c][h] = sum_d Wk[c][h*64+d] * score_w[h][d];  c0[h] = bk.score_w + score_b
__global__ void prep_u(const float* __restrict__ Wk, const float* __restrict__ score_w,
                       const float* __restrict__ bk, const float* __restrict__ score_b,
                       float* __restrict__ u, float* __restrict__ c0) {
    int tid = blockIdx.x * 256 + threadIdx.x;
    if (tid < D_MODEL * N_HEAD) {
        int c = tid >> 3, h = tid & 7;
        float s = 0.f;
        #pragma unroll 8
        for (int d = 0; d < D_HEAD; ++d)
            s += Wk[c * D_MODEL + h * D_HEAD + d] * score_w[h * D_HEAD + d];
        u[c * N_HEAD + h] = s;
    }
    if (blockIdx.x == 0 && threadIdx.x < N_HEAD) {
        int h = threadIdx.x;
        float s = score_b[h];
        for (int d = 0; d < D_HEAD; ++d)
            s += bk[h * D_HEAD + d] * score_w[h * D_HEAD + d];
        c0[h] = s;
    }
}

// Transpose K x N f32 -> N x K bf16
__global__ __launch_bounds__(256) void transpose_f32_to_bf16(
    const float* __restrict__ in, unsigned short* __restrict__ out, int K, int N) {
    __shared__ float tile[32][33];
    int n0 = blockIdx.x * 32, k0 = blockIdx.y * 32;
    int tx = threadIdx.x & 31, ty = threadIdx.x >> 5;
    #pragma unroll
    for (int i = ty; i < 32; i += 8)
        tile[i][tx] = in[(size_t)(k0 + i) * N + n0 + tx];
    __syncthreads();
    #pragma unroll
    for (int i = ty; i < 32; i += 8)
        out[(size_t)(n0 + i) * K + k0 + tx] = f2bf(tile[tx][i]);
}

// K1: per-batch scores -> softmax(n) -> pooled[b][h][c] (bf16)
__global__ __launch_bounds__(256) void score_pool(
    const float* __restrict__ x, const float* __restrict__ u,
    const float* __restrict__ c0, unsigned short* __restrict__ pooled) {
    __shared__ float s_attn[NTOK][N_HEAD + 1];  // pad to 9 to dodge bank conflicts
    int b = blockIdx.x;
    int tid = threadIdx.x;
    int l = tid & 63, w = tid >> 6;
    const float* xb = x + (size_t)b * NTOK * D_MODEL;

    // per-lane slice of u: channels l*8..l*8+7, all 8 heads (contiguous 64 floats)
    float ureg[64];
    {
        const float4* up = (const float4*)(u) + (size_t)l * 16;
        #pragma unroll
        for (int j = 0; j < 16; ++j) {
            float4 v = up[j];
            ureg[j * 4 + 0] = v.x; ureg[j * 4 + 1] = v.y;
            ureg[j * 4 + 2] = v.z; ureg[j * 4 + 3] = v.w;
        }
    }
    float c0r[8];
    #pragma unroll
    for (int h = 0; h < 8; ++h) c0r[h] = c0[h];

    // Phase A: scores.  wave w owns rows w*16..w*16+15; 64 lanes split channels.
    for (int rr = 0; rr < 16; ++rr) {
        int n = w * 16 + rr;
        const float4* xp = (const float4*)(xb + (size_t)n * D_MODEL) + l * 2;
        float4 x0 = xp[0], x1 = xp[1];
        float xv[8] = {x0.x, x0.y, x0.z, x0.w, x1.x, x1.y, x1.z, x1.w};
        float p[8] = {0, 0, 0, 0, 0, 0, 0, 0};
        #pragma unroll
        for (int i = 0; i < 8; ++i)
            #pragma unroll
            for (int h = 0; h < 8; ++h)
                p[h] += xv[i] * ureg[i * 8 + h];
        #pragma unroll
        for (int h = 0; h < 8; ++h) p[h] = wave_sum(p[h]);
        if (l == 0) {
            #pragma unroll
            for (int h = 0; h < 8; ++h) s_attn[n][h] = p[h] + c0r[h];
        }
    }
    __syncthreads();

    // Phase B: softmax over n (wave 0; lane = n)
    if (tid < 64) {
        int n = tid;
        #pragma unroll
        for (int h = 0; h < 8; ++h) {
            float s = s_attn[n][h];
            float m = wave_max(s);
            float e = __expf(s - m);
            float den = wave_sum(e);
            s_attn[n][h] = e / den;
        }
    }
    __syncthreads();

    // Phase C: pooled[h][c] = sum_n attn[n][h] * x[n][c]; thread owns 2 channels
    float acc[16];
    #pragma unroll
    for (int i = 0; i < 16; ++i) acc[i] = 0.f;
    int c2 = tid * 2;
    for (int n = 0; n < 64; ++n) {
        float2 xv = *(const float2*)(xb + (size_t)n * D_MODEL + c2);
        #pragma unroll
        for (int h = 0; h < 8; ++h) {
            float a = s_attn[n][h];
            acc[h * 2 + 0] += a * xv.x;
            acc[h * 2 + 1] += a * xv.y;
        }
    }
    unsigned short* pb = pooled + (size_t)b * N_HEAD * D_MODEL;
    #pragma unroll
    for (int h = 0; h < 8; ++h) {
        unsigned int packed = (unsigned int)f2bf(acc[h * 2]) |
                              ((unsigned int)f2bf(acc[h * 2 + 1]) << 16);
        *(unsigned int*)(pb + (size_t)h * D_MODEL + c2) = packed;
    }
}

// Shared MFMA GEMM: C[128 x 64] tile, A bf16 (row-major, lda), BT bf16 (N x K row-major).
// MODE 0: per-head proj (grid.y = head), bf16 out, +bias
// MODE 1: bf16 out, gelu(+bias)
// MODE 2: f32 out, +bias +residual(bf16)
template <int MODE>
__global__ __launch_bounds__(256) void gemm_ep(
    const unsigned short* __restrict__ A, int lda,
    const unsigned short* __restrict__ BT,
    const float* __restrict__ bias,
    void* __restrict__ Cout, int ldc,
    const unsigned short* __restrict__ res, int K) {
    __shared__ unsigned short Alds[128][72];
    __shared__ unsigned short Blds[64][72];
    int m0 = blockIdx.x * 128;
    int n0;
    const unsigned short* Ap = A;
    const unsigned short* Bp;
    const float* bp;
    if (MODE == 0) {
        int h = blockIdx.y;
        Ap = A + (size_t)h * 512;
        Bp = BT + (size_t)h * 64 * K;
        bp = bias + h * 64;
        n0 = h * 64;
    } else {
        n0 = blockIdx.y * 64;
        Bp = BT + (size_t)n0 * K;
        bp = bias + n0;
    }
    int tid = threadIdx.x, l = tid & 63, w = tid >> 6;
    int lr = l & 15, lq = l >> 4;

    f32x4 zero = {0.f, 0.f, 0.f, 0.f};
    f32x4 acc[2][4];
    #pragma unroll
    for (int mi = 0; mi < 2; ++mi)
        #pragma unroll
        for (int nj = 0; nj < 4; ++nj) acc[mi][nj] = zero;

    for (int k0 = 0; k0 < K; k0 += 64) {
        {   // stage A 128x64
            int r = tid >> 1, c = (tid & 1) * 32;
            const unsigned short* g = Ap + (size_t)(m0 + r) * lda + k0 + c;
            #pragma unroll
            for (int j = 0; j < 4; ++j)
                *(u16x8*)&Alds[r][c + j * 8] = *(const u16x8*)(g + j * 8);
        }
        {   // stage B^T 64x64
            int r = tid >> 2, c = (tid & 3) * 16;
            const unsigned short* g = Bp + (size_t)r * K + k0 + c;
            #pragma unroll
            for (int j = 0; j < 2; ++j)
                *(u16x8*)&Blds[r][c + j * 8] = *(const u16x8*)(g + j * 8);
        }
        __syncthreads();
        #pragma unroll
        for (int kk = 0; kk < 64; kk += 32) {
            int kb = kk + lq * 8;
            short8 a0 = *(const short8*)&Alds[w * 32 + lr][kb];
            short8 a1 = *(const short8*)&Alds[w * 32 + 16 + lr][kb];
            short8 b0 = *(const short8*)&Blds[lr][kb];
            short8 b1 = *(const short8*)&Blds[16 + lr][kb];
            short8 b2 = *(const short8*)&Blds[32 + lr][kb];
            short8 b3 = *(const short8*)&Blds[48 + lr][kb];
            acc[0][0] = __builtin_amdgcn_mfma_f32_16x16x32_bf16(a0, b0, acc[0][0], 0, 0, 0);
            acc[0][1] = __builtin_amdgcn_mfma_f32_16x16x32_bf16(a0, b1, acc[0][1], 0, 0, 0);
            acc[0][2] = __builtin_amdgcn_mfma_f32_16x16x32_bf16(a0, b2, acc[0][2], 0, 0, 0);
            acc[0][3] = __builtin_amdgcn_mfma_f32_16x16x32_bf16(a0, b3, acc[0][3], 0, 0, 0);
            acc[1][0] = __builtin_amdgcn_mfma_f32_16x16x32_bf16(a1, b0, acc[1][0], 0, 0, 0);
            acc[1][1] = __builtin_amdgcn_mfma_f32_16x16x32_bf16(a1, b1, acc[1][1], 0, 0, 0);
            acc[1][2] = __builtin_amdgcn_mfma_f32_16x16x32_bf16(a1, b2, acc[1][2], 0, 0, 0);
            acc[1][3] = __builtin_amdgcn_mfma_f32_16x16x32_bf16(a1, b3, acc[1][3], 0, 0, 0);
        }
        __syncthreads();
    }

    #pragma unroll
    for (int mi = 0; mi < 2; ++mi) {
        #pragma unroll
        for (int nj = 0; nj < 4; ++nj) {
            #pragma unroll
            for (int j = 0; j < 4; ++j) {
                int row = m0 + w * 32 + mi * 16 + lq * 4 + j;
                int nl = nj * 16 + lr;
                int col = n0 + nl;
                float v = acc[mi][nj][j] + bp[nl];
                if (MODE == 1) {
                    v = 0.5f * v * (1.0f + erff(v * 0.70710678118654752f));
                }
                if (MODE == 2) {
                    v += bf2f(res[(size_t)row * 512 + col]);
                    ((float*)Cout)[(size_t)row * ldc + col] = v;
                } else {
                    ((unsigned short*)Cout)[(size_t)row * ldc + col] = f2bf(v);
                }
            }
        }
    }
}

// K5: in-place LayerNorm over 512, one wave per row
__global__ __launch_bounds__(256) void ln_kernel(
    float* __restrict__ y, const float* __restrict__ g, const float* __restrict__ bta) {
    int row = blockIdx.x * 4 + (threadIdx.x >> 6);
    int l = threadIdx.x & 63;
    float* yp = y + (size_t)row * D_MODEL;
    float4 v0 = *(const float4*)(yp + l * 8);
    float4 v1 = *(const float4*)(yp + l * 8 + 4);
    float vv[8] = {v0.x, v0.y, v0.z, v0.w, v1.x, v1.y, v1.z, v1.w};
    float s = 0.f;
    #pragma unroll
    for (int i = 0; i < 8; ++i) s += vv[i];
    s = wave_sum(s);
    float mean = s * (1.f / 512.f);
    float q = 0.f;
    #pragma unroll
    for (int i = 0; i < 8; ++i) { float d = vv[i] - mean; q += d * d; }
    q = wave_sum(q);
    float rstd = rsqrtf(q * (1.f / 512.f) + 1e-5f);
    float4 g0 = *(const float4*)(g + l * 8);
    float4 g1 = *(const float4*)(g + l * 8 + 4);
    float4 b0 = *(const float4*)(bta + l * 8);
    float4 b1 = *(const float4*)(bta + l * 8 + 4);
    float gv[8] = {g0.x, g0.y, g0.z, g0.w, g1.x, g1.y, g1.z, g1.w};
    float bv[8] = {b0.x, b0.y, b0.z, b0.w, b1.x, b1.y, b1.z, b1.w};
    float ov[8];
    #pragma unroll
    for (int i = 0; i < 8; ++i) ov[i] = (vv[i] - mean) * rstd * gv[i] + bv[i];
    float4 o0 = {ov[0], ov[1], ov[2], ov[3]};
    float4 o1 = {ov[4], ov[5], ov[6], ov[7]};
    *(float4*)(yp + l * 8) = o0;
    *(float4*)(yp + l * 8 + 4) = o1;
}

extern "C" void kernel_launch(void* const* d_in, const int* in_sizes, int n_in,
                              void* d_out, int out_size, void* d_ws, size_t ws_size,
                              hipStream_t stream) {
    const float* x       = (const float*)d_in[0];
    const float* Wk      = (const float*)d_in[1];
    const float* bk      = (const float*)d_in[2];
    const float* Wv      = (const float*)d_in[3];
    const float* bv      = (const float*)d_in[4];
    const float* score_w = (const float*)d_in[5];
    const float* score_b = (const float*)d_in[6];
    const float* W1      = (const float*)d_in[7];
    const float* b1      = (const float*)d_in[8];
    const float* W2      = (const float*)d_in[9];
    const float* b2      = (const float*)d_in[10];
    const float* ln_g    = (const float*)d_in[11];
    const float* ln_b    = (const float*)d_in[12];
    float* out = (float*)d_out;

    char* ws = (char*)d_ws;
    size_t off = 0;
    auto alloc = [&](size_t sz) {
        void* p = ws + off;
        off = (off + sz + 1023) & ~(size_t)1023;
        return p;
    };
    float* u            = (float*)alloc((size_t)D_MODEL * N_HEAD * 4);
    float* c0           = (float*)alloc(N_HEAD * 4);
    unsigned short* WvT = (unsigned short*)alloc((size_t)512 * 512 * 2);
    unsigned short* W1T = (unsigned short*)alloc((size_t)2048 * 512 * 2);
    unsigned short* W2T = (unsigned short*)alloc((size_t)512 * 2048 * 2);
    unsigned short* pooled = (unsigned short*)alloc((size_t)BATCH * N_HEAD * D_MODEL * 2);
    unsigned short* feat   = (unsigned short*)alloc((size_t)BATCH * D_MODEL * 2);
    unsigned short* Hbuf   = (unsigned short*)alloc((size_t)BATCH * D_HIDDEN * 2);

    prep_u<<<dim3(16), dim3(256), 0, stream>>>(Wk, score_w, bk, score_b, u, c0);
    transpose_f32_to_bf16<<<dim3(16, 16), dim3(256), 0, stream>>>(Wv, WvT, 512, 512);
    transpose_f32_to_bf16<<<dim3(64, 16), dim3(256), 0, stream>>>(W1, W1T, 512, 2048);
    transpose_f32_to_bf16<<<dim3(16, 64), dim3(256), 0, stream>>>(W2, W2T, 2048, 512);
    score_pool<<<dim3(BATCH), dim3(256), 0, stream>>>(x, u, c0, pooled);
    // proj: feature = pooled @ Wv_blockdiag + bv   (grid.y = head)
    gemm_ep<0><<<dim3(32, 8), dim3(256), 0, stream>>>(
        pooled, N_HEAD * D_MODEL, WvT, bv, (void*)feat, D_MODEL,
        (const unsigned short*)nullptr, D_MODEL);
    // ffn1: H = gelu(feature @ W1 + b1)
    gemm_ep<1><<<dim3(32, 32), dim3(256), 0, stream>>>(
        feat, D_MODEL, W1T, b1, (void*)Hbuf, D_HIDDEN,
        (const unsigned short*)nullptr, D_MODEL);
    // ffn2: y = H @ W2 + b2 + feature   (f32 -> d_out)
    gemm_ep<2><<<dim3(32, 8), dim3(256), 0, stream>>>(
        Hbuf, D_HIDDEN, W2T, b2, (void*)out, D_MODEL, feat, D_HIDDEN);
    ln_kernel<<<dim3(1024), dim3(256), 0, stream>>>(out, ln_g, ln_b);
}